// Round 6
// baseline (333.459 us; speedup 1.0000x reference)
//
#include <hip/hip_runtime.h>
#include <math.h>

// Problem constants (fixed by setup_inputs)
#define NODES_TOT 7424      // 64 * 116
#define EDGES     237568    // NODES_TOT * 32
#define BATCH     64
#define NN        116
#define KDIM      7424      // FC K dim
#define N1        7424      // FC1 out
#define N2        13456     // FC2 out (116*116)
#define NKB       116       // KDIM / 64 k-steps total
#define KSPLIT1   8
#define KSPLIT2   4

typedef __attribute__((ext_vector_type(8))) short bf16x8;
typedef __attribute__((ext_vector_type(4))) float f32x4;
typedef __attribute__((ext_vector_type(4))) short s16x4;

__device__ __forceinline__ float mish_f(float v) {
    float sp = fmaxf(v, 0.0f) + log1pf(expf(-fabsf(v)));
    return v * tanhf(sp);
}

__device__ __forceinline__ unsigned short bf_rne(float f) {
    unsigned u = __float_as_uint(f);
    u += 0x7fffu + ((u >> 16) & 1u);
    return (unsigned short)(u >> 16);
}

__device__ __forceinline__ void gload_lds16(const void* g, void* l) {
    __builtin_amdgcn_global_load_lds(
        (const __attribute__((address_space(1))) void*)g,
        (__attribute__((address_space(3))) void*)l, 16, 0, 0);
}

// ---------- small utility ----------
__global__ void zero_kernel(int* __restrict__ p, int n) {
    int i = blockIdx.x * 256 + threadIdx.x;
    if (i < n) p[i] = 0;
}

// ---------- CSR build ----------
__global__ void hist_kernel(const int* __restrict__ dst, int* __restrict__ hist) {
    int e = blockIdx.x * 256 + threadIdx.x;
    if (e < EDGES) atomicAdd(&hist[dst[e]], 1);
}

__global__ void scan_kernel(const int* __restrict__ hist, int* __restrict__ row_start,
                            int* __restrict__ cursor) {
    __shared__ int s[1024];
    int t = threadIdx.x;
    int base = t * 8;
    int loc[8];
    int sum = 0;
    #pragma unroll
    for (int c = 0; c < 8; ++c) {
        int idx = base + c;
        int v = (idx < NODES_TOT) ? hist[idx] : 0;
        loc[c] = sum;
        sum += v;
    }
    s[t] = sum;
    __syncthreads();
    for (int off = 1; off < 1024; off <<= 1) {
        int v = (t >= off) ? s[t - off] : 0;
        __syncthreads();
        s[t] += v;
        __syncthreads();
    }
    int excl = s[t] - sum;
    #pragma unroll
    for (int c = 0; c < 8; ++c) {
        int idx = base + c;
        if (idx < NODES_TOT) {
            int r = excl + loc[c];
            row_start[idx] = r;
            cursor[idx] = r;
        }
    }
}

__global__ void csr_fill_kernel(const int* __restrict__ src, const int* __restrict__ dst,
                                int* __restrict__ cursor, int* __restrict__ csr_src) {
    int e = blockIdx.x * 256 + threadIdx.x;
    if (e < EDGES) {
        int p = atomicAdd(&cursor[dst[e]], 1);
        csr_src[p] = src[e];
    }
}

// ---------- fused mean-aggregate + SAGE linear + mish ----------
template <bool BF>
__global__ void __launch_bounds__(256) conv_kernel(
        const float* __restrict__ x, const int* __restrict__ csr_src,
        const int* __restrict__ row_start, const int* __restrict__ deg_arr,
        const float* __restrict__ w_l, const float* __restrict__ b_l,
        const float* __restrict__ w_r, void* __restrict__ h_out_v) {
    __shared__ float wlT[64 * 64];   // [k][f]
    __shared__ float wrT[64 * 64];   // [k][f]
    __shared__ float mv[4][64];
    __shared__ float xv[4][64];
    int t = threadIdx.x;
    for (int i = 0; i < 16; ++i) {
        int idx = t + i * 256;
        int f = idx >> 6, k = idx & 63;
        wlT[k * 64 + f] = w_l[idx];
        wrT[k * 64 + f] = w_r[idx];
    }
    int g = t >> 6, f = t & 63;
    __syncthreads();
    for (int nb = blockIdx.x * 4; nb < NODES_TOT; nb += gridDim.x * 4) {
        int node = nb + g;
        int deg = deg_arr[node];
        int rs = row_start[node];
        float sum = 0.f;
        for (int e = 0; e < deg; ++e) {
            int s = csr_src[rs + e];
            sum += x[s * 64 + f];
        }
        float mean = sum / (float)max(deg, 1);
        mv[g][f] = mean;
        xv[g][f] = x[node * 64 + f];
        __syncthreads();
        float o = b_l[f];
        #pragma unroll
        for (int k = 0; k < 64; ++k) {
            o = fmaf(mv[g][k], wlT[k * 64 + f], o);
            o = fmaf(xv[g][k], wrT[k * 64 + f], o);
        }
        float m = mish_f(o);
        if (BF) ((unsigned short*)h_out_v)[node * 64 + f] = bf_rne(m);
        else    ((float*)h_out_v)[node * 64 + f] = m;
        __syncthreads();
    }
}

// ---------- DMA-staged bf16-MFMA GEMM: Cp[by][64][N] = A[64][Ksl] * W[Ntile][Ksl]^T ----
// Both operands staged via global_load_lds (width 16): W as RAW fp32 (converted to
// bf16 on the consume side, 16 bf_rne/wave/step), A as bf16. Pre-swizzled global
// source <-> swizzled LDS read (same XOR involution): W granule(16B) ^= (row&7)<<1,
// A granule ^= row&7. Counted s_waitcnt vmcnt(6) keeps one full step's loads in
// flight across raw s_barriers; waves never register-stage anything.
template <int KS>
__global__ void __launch_bounds__(256) gemm_dma(
        const unsigned short* __restrict__ Abf, const float* __restrict__ W,
        float* __restrict__ Cp, int N) {
    __shared__ __align__(16) float          Wlds[2][4096];   // [buf][row(64)][64 f32]
    __shared__ __align__(16) unsigned short Alds[2][4096];   // [buf][row(64)][64 bf16]
    int t = threadIdx.x;
    int bx = blockIdx.x, by = blockIdx.y;
    int kb0 = (by * NKB) / KS;
    int kb1 = ((by + 1) * NKB) / KS;
    int S = kb1 - kb0;
    int n0 = bx * 64;
    int wv = t >> 6, l = t & 63, l15 = l & 15, hi = l >> 4;

    // staging source pointers (per thread), pre-swizzled granules
    const float* wsrc[4];
    #pragma unroll
    for (int ii = 0; ii < 4; ++ii) {
        int rloc = wv * 16 + ii * 4 + (l >> 4);         // LDS row 0..63
        int wr = n0 + rloc; if (wr >= N) wr = N - 1;
        int g = (l & 15) ^ ((rloc & 7) << 1);           // 16B granule (4 f32)
        wsrc[ii] = W + (size_t)wr * KDIM + (size_t)kb0 * 64 + g * 4;
    }
    const unsigned short* asrcp[2];
    #pragma unroll
    for (int ii = 0; ii < 2; ++ii) {
        int rloc = wv * 16 + ii * 8 + (l >> 3);         // LDS row 0..63
        int g = (l & 7) ^ (rloc & 7);                   // 16B granule (8 bf16)
        asrcp[ii] = Abf + (size_t)rloc * KDIM + (size_t)kb0 * 64 + g * 8;
    }

    f32x4 acc[4];
    #pragma unroll
    for (int g = 0; g < 4; ++g) acc[g] = (f32x4){0.f, 0.f, 0.f, 0.f};

#define ISSUE(step, buf) do {                                              \
        size_t ko = (size_t)(step) * 64;                                   \
        _Pragma("unroll")                                                  \
        for (int ii = 0; ii < 4; ++ii)                                     \
            gload_lds16(wsrc[ii] + ko, &Wlds[buf][(wv * 16 + ii * 4) * 64]); \
        _Pragma("unroll")                                                  \
        for (int ii = 0; ii < 2; ++ii)                                     \
            gload_lds16(asrcp[ii] + ko, &Alds[buf][(wv * 16 + ii * 8) * 64]); \
    } while (0)

#define MFMAPH(buf) do {                                                   \
        _Pragma("unroll")                                                  \
        for (int s = 0; s < 2; ++s) {                                      \
            int fw = s * 4 + hi;                                           \
            int n = wv * 16 + l15;                                         \
            int g0 = (2 * fw) ^ ((n & 7) << 1);                            \
            f32x4 wlo = *(const f32x4*)&Wlds[buf][n * 64 + g0 * 4];        \
            f32x4 whi = *(const f32x4*)&Wlds[buf][n * 64 + g0 * 4 + 4];    \
            bf16x8 bh;                                                     \
            _Pragma("unroll")                                              \
            for (int j = 0; j < 4; ++j) {                                  \
                bh[j]     = (short)bf_rne(wlo[j]);                         \
                bh[4 + j] = (short)bf_rne(whi[j]);                         \
            }                                                              \
            _Pragma("unroll")                                              \
            for (int g = 0; g < 4; ++g) {                                  \
                int ar = g * 16 + l15;                                     \
                bf16x8 av = *(const bf16x8*)&Alds[buf][ar * 64 + ((fw ^ (ar & 7)) * 8)]; \
                acc[g] = __builtin_amdgcn_mfma_f32_16x16x32_bf16(av, bh, acc[g], 0, 0, 0); \
            }                                                              \
        }                                                                  \
    } while (0)

#define WAIT6()  asm volatile("s_waitcnt vmcnt(6)" ::: "memory")
#define WAIT0()  asm volatile("s_waitcnt vmcnt(0)" ::: "memory")
#define RBAR()   asm volatile("s_barrier" ::: "memory")
#define LBAR()   asm volatile("s_waitcnt lgkmcnt(0)\n\ts_barrier" ::: "memory")

    // prologue (S >= 14 always)
    ISSUE(0, 0);
    ISSUE(1, 1);
    WAIT6();            // step 0 landed (leave step 1's 6 in flight)
    RBAR();

    int i = 0;
    while (true) {
        MFMAPH(0);                       // consume step i (buf 0)
        LBAR();                          // all readers done with buf 0
        if (i + 2 < S) { ISSUE(i + 2, 0); WAIT6(); } else { WAIT0(); }
        RBAR();                          // step i+1 landed for all waves
        if (++i == S) break;
        MFMAPH(1);                       // consume step i (buf 1)
        LBAR();
        if (i + 2 < S) { ISSUE(i + 2, 1); WAIT6(); } else { WAIT0(); }
        RBAR();
        if (++i == S) break;
    }

#undef ISSUE
#undef MFMAPH
#undef WAIT6
#undef WAIT0
#undef RBAR
#undef LBAR

    // store partials
    int gn = n0 + wv * 16 + l15;
    if (gn < N) {
        float* cp = Cp + (size_t)by * 64 * N;
        #pragma unroll
        for (int g = 0; g < 4; ++g)
            #pragma unroll
            for (int rr = 0; rr < 4; ++rr)
                cp[(size_t)(g * 16 + hi * 4 + rr) * N + gn] = acc[g][rr];
    }
}

// ---------- reduce partials + bias + mish + bf16 cast (FC1 epilogue) ----------
__global__ void reduce1_kernel(const float* __restrict__ Cp, const float* __restrict__ b,
                               unsigned short* __restrict__ A2) {
    int i4 = (blockIdx.x * 256 + threadIdx.x) * 4;
    if (i4 >= BATCH * N1) return;
    int n = i4 % N1;
    f32x4 acc = *(const f32x4*)(b + n);
    #pragma unroll
    for (int s = 0; s < KSPLIT1; ++s)
        acc += *(const f32x4*)(Cp + (size_t)s * BATCH * N1 + i4);
    s16x4 o;
    #pragma unroll
    for (int j = 0; j < 4; ++j) o[j] = (short)bf_rne(mish_f(acc[j]));
    *(s16x4*)(A2 + i4) = o;
}

// ---------- reduce partials + bias (FC2 epilogue) ----------
__global__ void reduce2_kernel(const float* __restrict__ Cp, const float* __restrict__ b,
                               float* __restrict__ C2) {
    int i4 = (blockIdx.x * 256 + threadIdx.x) * 4;
    if (i4 >= BATCH * N2) return;
    int n = i4 % N2;
    f32x4 acc = *(const f32x4*)(b + n);
    #pragma unroll
    for (int s = 0; s < KSPLIT2; ++s)
        acc += *(const f32x4*)(Cp + (size_t)s * BATCH * N2 + i4);
    *(f32x4*)(C2 + i4) = acc;
}

// ---------- symmetrize + unit diagonal (C2 L2-resident, bias pre-added) ----------
__global__ void sym_kernel(const float* __restrict__ C2, float* __restrict__ out) {
    int tid = blockIdx.x * 256 + threadIdx.x;
    if (tid >= BATCH * NN * NN) return;
    int j = tid % NN;
    int r = tid / NN;
    int i = r % NN;
    int b = r / NN;
    float v;
    if (i == j) {
        v = 1.0f;
    } else {
        v = 0.5f * (C2[(size_t)b * N2 + i * NN + j] + C2[(size_t)b * N2 + j * NN + i]);
    }
    out[tid] = v;
}

extern "C" void kernel_launch(void* const* d_in, const int* in_sizes, int n_in,
                              void* d_out, int out_size, void* d_ws, size_t ws_size,
                              hipStream_t stream) {
    const float* z     = (const float*)d_in[0];
    const int*   edge  = (const int*)d_in[1];
    const float* w1_l  = (const float*)d_in[3];
    const float* b1_l  = (const float*)d_in[4];
    const float* w1_r  = (const float*)d_in[5];
    const float* w2_l  = (const float*)d_in[6];
    const float* b2_l  = (const float*)d_in[7];
    const float* w2_r  = (const float*)d_in[8];
    const float* fc1_w = (const float*)d_in[9];
    const float* fc1_b = (const float*)d_in[10];
    const float* fc2_w = (const float*)d_in[11];
    const float* fc2_b = (const float*)d_in[12];
    float* out = (float*)d_out;

    char* ws = (char*)d_ws;
    size_t off = 0;
    auto alloc = [&](size_t bytes) {
        void* p = ws + off;
        off = (off + bytes + 255) & ~(size_t)255;
        return p;
    };
    int*            hist      = (int*)alloc(NODES_TOT * 4);
    int*            row_start = (int*)alloc(NODES_TOT * 4);
    int*            cursor    = (int*)alloc(NODES_TOT * 4);
    int*            csr_src   = (int*)alloc((size_t)EDGES * 4);
    float*          h1        = (float*)alloc((size_t)NODES_TOT * 64 * 4);
    unsigned short* A1        = (unsigned short*)alloc((size_t)NODES_TOT * 64 * 2);
    float*          Cp1       = (float*)alloc((size_t)KSPLIT1 * BATCH * N1 * 4);
    unsigned short* A2        = (unsigned short*)alloc((size_t)BATCH * N1 * 2);
    float*          Cp2       = (float*)alloc((size_t)KSPLIT2 * BATCH * N2 * 4);
    float*          C2        = (float*)alloc((size_t)BATCH * N2 * 4);

    const int* src = edge;
    const int* dst = edge + EDGES;

    zero_kernel<<<(NODES_TOT + 255) / 256, 256, 0, stream>>>(hist, NODES_TOT);
    hist_kernel<<<(EDGES + 255) / 256, 256, 0, stream>>>(dst, hist);
    scan_kernel<<<1, 1024, 0, stream>>>(hist, row_start, cursor);
    csr_fill_kernel<<<(EDGES + 255) / 256, 256, 0, stream>>>(src, dst, cursor, csr_src);

    conv_kernel<false><<<928, 256, 0, stream>>>(z, csr_src, row_start, hist, w1_l, b1_l, w1_r, h1);
    conv_kernel<true><<<928, 256, 0, stream>>>(h1, csr_src, row_start, hist, w2_l, b2_l, w2_r, A1);

    // FC1: partials over 8 k-splits, then fused reduce+bias+mish+cast
    gemm_dma<KSPLIT1><<<dim3(N1 / 64, KSPLIT1), 256, 0, stream>>>(A1, fc1_w, Cp1, N1);
    reduce1_kernel<<<(BATCH * N1 / 4 + 255) / 256, 256, 0, stream>>>(Cp1, fc1_b, A2);

    // FC2: partials over 4 k-splits
    gemm_dma<KSPLIT2><<<dim3((N2 + 63) / 64, KSPLIT2), 256, 0, stream>>>(A2, fc2_w, Cp2, N2);
    reduce2_kernel<<<(BATCH * N2 / 4 + 255) / 256, 256, 0, stream>>>(Cp2, fc2_b, C2);

    sym_kernel<<<(BATCH * NN * NN + 255) / 256, 256, 0, stream>>>(C2, out);
}